// Round 1
// baseline (1739.174 us; speedup 1.0000x reference)
//
#include <hip/hip_runtime.h>
#include <hip/hip_bf16.h>
#include <stdint.h>

// Problem constants
// B=4 N=4 -> 16 batch instances; CX=512 CF=256 HID=256 OUT=512 H=W=48 -> P=2304
#define PPIX 2304L
#define FEATC 1536

typedef __attribute__((ext_vector_type(8))) short short8;
typedef __attribute__((ext_vector_type(4))) short short4v;
typedef __attribute__((ext_vector_type(4))) float f32x4;

__device__ __forceinline__ short f2bf(float f) {
  union { float f; uint32_t u; } v; v.f = f;
  return (short)((v.u + 0x7fffu + ((v.u >> 16) & 1u)) >> 16);
}

// ---------------- elementwise f32 -> bf16 (vectorized x4) ----------------
__global__ void k_conv_bf16(const float* __restrict__ src, short* __restrict__ dst, long n4) {
  long i = (long)blockIdx.x * blockDim.x + threadIdx.x;
  long stride = (long)gridDim.x * blockDim.x;
  for (long j = i; j < n4; j += stride) {
    float4 v = ((const float4*)src)[j];
    short4v o;
    o[0] = f2bf(v.x); o[1] = f2bf(v.y); o[2] = f2bf(v.z); o[3] = f2bf(v.w);
    ((short4v*)dst)[j] = o;
  }
}

// ---------------- tiled transpose f32 [R][C] -> bf16 [C][R] (ldDst), rep dst slots ----------------
__global__ __launch_bounds__(256) void k_transpose_bf16(
    const float* __restrict__ src, long srcZ,
    short* __restrict__ dst, long dstZ,
    int srcCols, int ldDst, int rep) {
  __shared__ float tile[32][33];
  const int z = blockIdx.z;
  const float* s = src + (long)z * srcZ;
  const int c0 = blockIdx.x * 32, r0 = blockIdx.y * 32;
  #pragma unroll
  for (int j = 0; j < 4; j++)
    tile[threadIdx.y + j * 8][threadIdx.x] =
        s[(long)(r0 + threadIdx.y + j * 8) * srcCols + c0 + threadIdx.x];
  __syncthreads();
  short vals[4];
  #pragma unroll
  for (int j = 0; j < 4; j++) vals[j] = f2bf(tile[threadIdx.x][threadIdx.y + j * 8]);
  for (int rr = 0; rr < rep; rr++) {
    short* d = dst + (long)(z * rep + rr) * dstZ;
    #pragma unroll
    for (int j = 0; j < 4; j++)
      d[(long)(c0 + threadIdx.y + j * 8) * ldDst + r0 + threadIdx.x] = vals[j];
  }
}

// ---------------- row softmax: S f32 [z][2304][2304] -> P bf16 ----------------
__global__ __launch_bounds__(256) void k_softmax(const float* __restrict__ S, short* __restrict__ P) {
  __shared__ float red[8];
  const long base = ((long)blockIdx.y * 2304 + blockIdx.x) * 2304;
  const float* s = S + base;
  short* p = P + base;
  const int t = threadIdx.x;
  float v[9];
  float mx = -3.4e38f;
  #pragma unroll
  for (int j = 0; j < 9; j++) { v[j] = s[t + j * 256]; mx = fmaxf(mx, v[j]); }
  #pragma unroll
  for (int o = 32; o >= 1; o >>= 1) mx = fmaxf(mx, __shfl_xor(mx, o));
  if ((t & 63) == 0) red[t >> 6] = mx;
  __syncthreads();
  mx = fmaxf(fmaxf(red[0], red[1]), fmaxf(red[2], red[3]));
  float sum = 0.f;
  #pragma unroll
  for (int j = 0; j < 9; j++) { v[j] = __expf(v[j] - mx); sum += v[j]; }
  #pragma unroll
  for (int o = 32; o >= 1; o >>= 1) sum += __shfl_xor(sum, o);
  if ((t & 63) == 0) red[4 + (t >> 6)] = sum;
  __syncthreads();
  sum = red[4] + red[5] + red[6] + red[7];
  float inv = 1.f / sum;
  #pragma unroll
  for (int j = 0; j < 9; j++) p[t + j * 256] = f2bf(v[j] * inv);
}

// ---------------- generic bf16 MFMA GEMM: C[m][n] = sum_k A[m][k]*Bt[n][k] (+bias) ----------------
// 128x128 tile, BK=32, 4 waves (2x2), 4x4 16x16x32 frags per wave. Reg-staged LDS.
// Per-operand batch offset: ptr + ((i0+z)/div)*str
template<int BIAS_MODE, int OUT_F32>   // BIAS_MODE: 0 none, 1 per-row(m), 2 per-col(n)
__global__ __launch_bounds__(256) void k_gemm_bt(
    const short* __restrict__ Ab, long aStr, int aDiv, int aI0, int lda,
    const short* __restrict__ Bb, long bStr, int bDiv, int bI0, int ldb,
    void* __restrict__ Cb, long cStr, int cDiv, int cI0, int ldc,
    const float* __restrict__ bias, int K) {
  __shared__ short As[128 * 32];
  __shared__ short Bs[128 * 32];
  const int z = blockIdx.z;
  const short* A = Ab + (long)((aI0 + z) / aDiv) * aStr;
  const short* B = Bb + (long)((bI0 + z) / bDiv) * bStr;
  const int m0 = blockIdx.y * 128, n0 = blockIdx.x * 128;
  const int t = threadIdx.x;
  const int lane = t & 63, wave = t >> 6;
  const int wr = wave >> 1, wc = wave & 1;

  // staging: thread t covers rows t>>2 and 64+(t>>2), k-chunk (t&3)*8 (16B)
  const int sr = t >> 2;
  const int sc = (t & 3) * 8;
  const short* Ag0 = A + (long)(m0 + sr) * lda + sc;
  const short* Ag1 = A + (long)(m0 + 64 + sr) * lda + sc;
  const short* Bg0 = B + (long)(n0 + sr) * ldb + sc;
  const short* Bg1 = B + (long)(n0 + 64 + sr) * ldb + sc;
  short* As0 = &As[sr * 32 + sc];
  short* As1 = &As[(64 + sr) * 32 + sc];
  short* Bs0 = &Bs[sr * 32 + sc];
  short* Bs1 = &Bs[(64 + sr) * 32 + sc];

  f32x4 acc[4][4];
  #pragma unroll
  for (int i = 0; i < 4; i++)
    #pragma unroll
    for (int j = 0; j < 4; j++)
      acc[i][j] = (f32x4){0.f, 0.f, 0.f, 0.f};

  const int fr = lane & 15;        // frag row within 16 (m or n)
  const int fk = (lane >> 4) * 8;  // frag k offset (8 contiguous bf16)

  for (int k0 = 0; k0 < K; k0 += 32) {
    short8 a0 = *(const short8*)(Ag0 + k0);
    short8 a1 = *(const short8*)(Ag1 + k0);
    short8 b0 = *(const short8*)(Bg0 + k0);
    short8 b1 = *(const short8*)(Bg1 + k0);
    __syncthreads();
    *(short8*)As0 = a0;
    *(short8*)As1 = a1;
    *(short8*)Bs0 = b0;
    *(short8*)Bs1 = b1;
    __syncthreads();
    short8 af[4], bfr[4];
    #pragma unroll
    for (int mf = 0; mf < 4; mf++)
      af[mf] = *(const short8*)&As[(wr * 64 + mf * 16 + fr) * 32 + fk];
    #pragma unroll
    for (int nf = 0; nf < 4; nf++)
      bfr[nf] = *(const short8*)&Bs[(wc * 64 + nf * 16 + fr) * 32 + fk];
    #pragma unroll
    for (int mf = 0; mf < 4; mf++)
      #pragma unroll
      for (int nf = 0; nf < 4; nf++)
        acc[mf][nf] = __builtin_amdgcn_mfma_f32_16x16x32_bf16(af[mf], bfr[nf], acc[mf][nf], 0, 0, 0);
  }

  // C/D frag layout (m89-verified): col = lane&15, row = (lane>>4)*4 + j
  const int cc = lane & 15;
  const int rg = (lane >> 4) * 4;
  const long coff = (long)((cI0 + z) / cDiv) * cStr;
  #pragma unroll
  for (int mf = 0; mf < 4; mf++) {
    #pragma unroll
    for (int nf = 0; nf < 4; nf++) {
      #pragma unroll
      for (int j = 0; j < 4; j++) {
        int m = m0 + wr * 64 + mf * 16 + rg + j;
        int n = n0 + wc * 64 + nf * 16 + cc;
        float v = acc[mf][nf][j];
        if (BIAS_MODE == 1) v += bias[m];
        if (BIAS_MODE == 2) v += bias[n];
        if (OUT_F32) ((float*)Cb)[coff + (long)m * ldc + n] = v;
        else         ((short*)Cb)[coff + (long)m * ldc + n] = f2bf(v);
      }
    }
  }
}

extern "C" void kernel_launch(void* const* d_in, const int* in_sizes, int n_in,
                              void* d_out, int out_size, void* d_ws, size_t ws_size,
                              hipStream_t stream) {
  const float* mv  = (const float*)d_in[0];   // [16][512][2304]
  const float* ff  = (const float*)d_in[1];   // [4][256][2304]
  const float* wq1 = (const float*)d_in[2];   // [256][512]
  const float* bq1 = (const float*)d_in[3];
  const float* wk1 = (const float*)d_in[4];   // [256][256]
  const float* bk1 = (const float*)d_in[5];
  const float* wq2 = (const float*)d_in[6];   // [256][256]
  const float* bq2 = (const float*)d_in[7];
  const float* wk2 = (const float*)d_in[8];   // [256][512]
  const float* bk2 = (const float*)d_in[9];
  const float* wdr = (const float*)d_in[10];  // [512][1536]
  const float* bdr = (const float*)d_in[11];
  float* out = (float*)d_out;                 // [16][512][2304]

  // ---- carve workspace ----
  unsigned char* w = (unsigned char*)d_ws;
  auto carve = [&](size_t bytes) -> short* {
    short* r = (short*)w;
    w += (bytes + 255) & ~(size_t)255;
    return r;
  };
  const long FEAT_Z = PPIX * FEATC;            // per-i featT elements
  const long QKZ = PPIX * 256;                 // per-slot Q/K elements
  const long SZ = PPIX * PPIX;
  short* featT = carve(16 * FEAT_Z * 2);       // [16][2304][1536] bf16
  short* mv_bf = carve(16L * 512 * PPIX * 2);  // [16][512][2304]
  short* ff_bf = carve(4L * 256 * PPIX * 2);   // [4][256][2304]
  short* q1t   = carve(16 * QKZ * 2);
  short* k2t   = carve(16 * QKZ * 2);
  short* q2t   = carve(4 * QKZ * 2);
  short* k1t   = carve(4 * QKZ * 2);
  short* wq1b  = carve(256L * 512 * 2);
  short* wk1b  = carve(256L * 256 * 2);
  short* wq2b  = carve(256L * 256 * 2);
  short* wk2b  = carve(256L * 512 * 2);
  short* wdrb  = carve(512L * 1536 * 2);

  size_t used = (size_t)(w - (unsigned char*)d_ws);
  const size_t perz = (size_t)SZ * 4 + (size_t)SZ * 2;  // S f32 + P bf16 per z (both 256B-mult)
  int zb = 1;
  {
    const int cands[5] = {16, 8, 4, 2, 1};
    for (int c = 0; c < 5; c++) {
      if (used + (size_t)cands[c] * perz <= ws_size) { zb = cands[c]; break; }
    }
  }
  float* Sbuf = (float*)carve((size_t)zb * SZ * 4);
  short* Pbuf = carve((size_t)zb * SZ * 2);

  // ---- prep: converts ----
  auto conv = [&](const float* s, short* d, long n) {
    long blocks = (n / 4 + 255) / 256;
    if (blocks > 2048) blocks = 2048;
    k_conv_bf16<<<dim3((int)blocks), dim3(256), 0, stream>>>(s, d, n / 4);
  };
  conv(mv, mv_bf, 16L * 512 * PPIX);
  conv(ff, ff_bf, 4L * 256 * PPIX);
  conv(wq1, wq1b, 256L * 512);
  conv(wk1, wk1b, 256L * 256);
  conv(wq2, wq2b, 256L * 256);
  conv(wk2, wk2b, 256L * 512);
  conv(wdr, wdrb, 512L * 1536);

  // ---- prep: transposes into featT (cols 0-511 = mvT, 1024-1279 = ffT) ----
  k_transpose_bf16<<<dim3(72, 16, 16), dim3(32, 8), 0, stream>>>(
      mv, 512L * PPIX, featT, FEAT_Z, (int)PPIX, FEATC, 1);
  k_transpose_bf16<<<dim3(72, 8, 4), dim3(32, 8), 0, stream>>>(
      ff, 256L * PPIX, featT + 1024, FEAT_Z, (int)PPIX, FEATC, 4);

  // ---- generic GEMM launcher ----
  auto gemm = [&](int biasMode, int outF32,
                  const short* A, long aStr, int aDiv, int aI0, int lda,
                  const short* B, long bStr, int bDiv, int bI0, int ldb,
                  void* C, long cStr, int cDiv, int cI0, int ldc,
                  const float* bias, int M, int N, int K, int Z) {
    dim3 g(N / 128, M / 128, Z), b(256);
    if (biasMode == 2 && !outF32)
      k_gemm_bt<2, 0><<<g, b, 0, stream>>>(A, aStr, aDiv, aI0, lda, B, bStr, bDiv, bI0, ldb,
                                           C, cStr, cDiv, cI0, ldc, bias, K);
    else if (biasMode == 0 && outF32)
      k_gemm_bt<0, 1><<<g, b, 0, stream>>>(A, aStr, aDiv, aI0, lda, B, bStr, bDiv, bI0, ldb,
                                           C, cStr, cDiv, cI0, ldc, bias, K);
    else if (biasMode == 0 && !outF32)
      k_gemm_bt<0, 0><<<g, b, 0, stream>>>(A, aStr, aDiv, aI0, lda, B, bStr, bDiv, bI0, ldb,
                                           C, cStr, cDiv, cI0, ldc, bias, K);
    else
      k_gemm_bt<1, 1><<<g, b, 0, stream>>>(A, aStr, aDiv, aI0, lda, B, bStr, bDiv, bI0, ldb,
                                           C, cStr, cDiv, cI0, ldc, bias, K);
  };

  // ---- projections ----
  // Q1T[i][p][h] = sum_c mvT[i][p][c]*wq1[h][c] + bq1[h]
  gemm(2, 0, featT, FEAT_Z, 1, 0, FEATC,  wq1b, 0, 1, 0, 512,
       q1t, QKZ, 1, 0, 256,  bq1, (int)PPIX, 256, 512, 16);
  // K2T[i][q][h] = sum_c mvT[i][q][c]*wk2[h][c] + bk2[h]
  gemm(2, 0, featT, FEAT_Z, 1, 0, FEATC,  wk2b, 0, 1, 0, 512,
       k2t, QKZ, 1, 0, 256,  bk2, (int)PPIX, 256, 512, 16);
  // Q2T[b][p][h] = sum_c ffT[b][p][c]*wq2[h][c] + bq2[h]   (ffT read from featT slot b*4)
  gemm(2, 0, featT + 1024, 4 * FEAT_Z, 1, 0, FEATC,  wq2b, 0, 1, 0, 256,
       q2t, QKZ, 1, 0, 256,  bq2, (int)PPIX, 256, 256, 4);
  // K1T[b][q][h] = sum_c ffT[b][q][c]*wk1[h][c] + bk1[h]
  gemm(2, 0, featT + 1024, 4 * FEAT_Z, 1, 0, FEATC,  wk1b, 0, 1, 0, 256,
       k1t, QKZ, 1, 0, 256,  bk1, (int)PPIX, 256, 256, 4);

  // ---- attention (chunks of zb batches) ----
  for (int i0 = 0; i0 < 16; i0 += zb) {
    // layer 1: S = Q1T_i x K1T_b^T ; P = softmax(S) ; O1 = P x ff_b^T -> featT cols 1280-1535
    gemm(0, 1, q1t, QKZ, 1, i0, 256,  k1t, QKZ, 4, i0, 256,
         Sbuf, SZ, 1, 0, (int)PPIX,  nullptr, (int)PPIX, (int)PPIX, 256, zb);
    k_softmax<<<dim3(2304, zb), dim3(256), 0, stream>>>(Sbuf, Pbuf);
    gemm(0, 0, Pbuf, SZ, 1, 0, (int)PPIX,  ff_bf, 256L * PPIX, 4, i0, (int)PPIX,
         featT + 1280, FEAT_Z, 1, i0, FEATC,  nullptr, (int)PPIX, 256, (int)PPIX, zb);
    // layer 2: S = Q2T_b x K2T_i^T ; P = softmax(S) ; O2 = P x mv_i^T -> featT cols 512-1023
    gemm(0, 1, q2t, QKZ, 4, i0, 256,  k2t, QKZ, 1, i0, 256,
         Sbuf, SZ, 1, 0, (int)PPIX,  nullptr, (int)PPIX, (int)PPIX, 256, zb);
    k_softmax<<<dim3(2304, zb), dim3(256), 0, stream>>>(Sbuf, Pbuf);
    gemm(0, 0, Pbuf, SZ, 1, 0, (int)PPIX,  mv_bf, 512L * PPIX, 1, i0, (int)PPIX,
         featT + 512, FEAT_Z, 1, i0, FEATC,  nullptr, (int)PPIX, 512, (int)PPIX, zb);
  }

  // ---- final 1x1 conv: out[i][o][p] = sum_ch wdr[o][ch]*featT[i][p][ch] + bdr[o] ----
  gemm(1, 1, wdrb, 0, 1, 0, FEATC,  featT, FEAT_Z, 1, 0, FEATC,
       out, 512L * PPIX, 1, 0, (int)PPIX,  bdr, 512, (int)PPIX, FEATC, 16);

  (void)in_sizes; (void)n_in; (void)out_size; (void)ws_size;
}